// Round 9
// baseline (619.732 us; speedup 1.0000x reference)
//
#include <hip/hip_runtime.h>
#include <hip/hip_bf16.h>
#include <math.h>

#define N_Q 16384
#define N_M 16384
#define DIM 128
#define KNN 5
#define SPLITS 8
#define COLS_PER_SPLIT (N_M / SPLITS)   // 2048
#define ITERS (COLS_PER_SPLIT / 128)    // 16
#define BROWS 256                        // rows per block (4 waves x 64)
#define TSEL 8                           // keys kept per (row, split)
#define LLIST 4                          // per-lane sorted list depth
#define BIGF 3.0e38f

typedef __bf16 bf16x8 __attribute__((ext_vector_type(8)));
typedef float f32x4 __attribute__((ext_vector_type(4)));

__device__ __forceinline__ void gl2lds16(const void* g, void* l) {
    __builtin_amdgcn_global_load_lds(
        (const __attribute__((address_space(1))) void*)g,
        (__attribute__((address_space(3))) void*)l, 16, 0, 0);
}

// med3: with a<=b (sorted list invariant), med3(a,b,k) == max(a, min(b,k)).
__device__ __forceinline__ unsigned umed3(unsigned a, unsigned b, unsigned c) {
    unsigned d;
    asm("v_med3_u32 %0, %1, %2, %3" : "=v"(d) : "v"(a), "v"(b), "v"(c));
    return d;
}

// branchless sorted insert (ascending), depth D: (D-1) med3 + 1 min.
template <int D>
__device__ __forceinline__ void insD(unsigned (&L)[D], unsigned k) {
#pragma unroll
    for (int i = D - 1; i >= 1; --i) L[i] = umed3(L[i - 1], L[i], k);
    L[0] = min(L[0], k);
}

// ---------------------------------------------------------------------------
// Kernel A: per-row sumsq + bf16 conversion + biased m2. Also re-zeroes the
// per-row-group completion counters every launch (graph replays stay
// correct: prep->knn kernel boundary orders the zeroing before any atomic).
// ---------------------------------------------------------------------------
__global__ void prep_kernel(const float* __restrict__ q,
                            const float* __restrict__ mem,
                            float* __restrict__ q2, float* __restrict__ m2,
                            float* __restrict__ m2b,
                            __hip_bfloat16* __restrict__ qb,
                            __hip_bfloat16* __restrict__ mb,
                            unsigned* __restrict__ cnt) {
    if (blockIdx.x == 0 && threadIdx.x < 64) cnt[threadIdx.x] = 0;
    int gt = blockIdx.x * blockDim.x + threadIdx.x;
    int wid = gt >> 6;
    int lane = gt & 63;
    bool isq = wid < N_Q;
    int r = isq ? wid : wid - N_Q;
    const float* src = (isq ? q : mem) + (size_t)r * DIM;
    __hip_bfloat16* bdst = (isq ? qb : mb) + (size_t)r * DIM;
    float2 v = reinterpret_cast<const float2*>(src)[lane];
    float sc = isq ? 1.0f : -2.0f;   // B operand carries the -2 factor
    __hip_bfloat162 bv;
    bv.x = __float2bfloat16(sc * v.x);
    bv.y = __float2bfloat16(sc * v.y);
    reinterpret_cast<__hip_bfloat162*>(bdst)[lane] = bv;
    float s = fmaf(v.x, v.x, v.y * v.y);
#pragma unroll
    for (int off = 32; off > 0; off >>= 1) s += __shfl_down(s, off, 64);
    if (lane == 0) {
        if (isq) {
            q2[r] = s;
        } else {
            m2[r] = s;
            m2b[r] = s + 256.0f;  // key = m2b-2dot >= ~216 > 0 always
        }
    }
}

// ---- MFMA for one chunk (2 column-groups of 16) into the given acc set ----
__device__ __forceinline__ void mfma_chunk(const unsigned char* cbuf,
                                           int lds_base,
                                           const bf16x8 (&afrag)[4][4],
                                           const float (&m2r)[8], int c,
                                           f32x4 (&acc)[4][2]) {
#pragma unroll
    for (int ti = 0; ti < 4; ++ti)
#pragma unroll
        for (int c2 = 0; c2 < 2; ++c2) {
            float m = m2r[c * 2 + c2];
            acc[ti][c2] = (f32x4){m, m, m, m};
        }
#pragma unroll
    for (int ks = 0; ks < 4; ++ks) {
        const unsigned char* bp =
            cbuf + (lds_base ^ (ks << 6)) + (c >> 1) * 16384;
#pragma unroll
        for (int c2 = 0; c2 < 2; ++c2) {
            bf16x8 bfr = *reinterpret_cast<const bf16x8*>(
                bp + ((c & 1) * 2 + c2) * 4096);
#pragma unroll
            for (int ti = 0; ti < 4; ++ti)
                acc[ti][c2] = __builtin_amdgcn_mfma_f32_16x16x32_bf16(
                    afrag[ti][ks], bfr, acc[ti][c2], 0, 0, 0);
        }
    }
}

// ---- pack + insert the 32 keys of one finished chunk ----
__device__ __forceinline__ void select_chunk(unsigned (&lst)[16][LLIST],
                                             const f32x4 (&acc)[4][2],
                                             unsigned cv0, unsigned cv1) {
#pragma unroll
    for (int ti = 0; ti < 4; ++ti)
#pragma unroll
        for (int r = 0; r < 4; ++r) {
            const int rr = ti * 4 + r;
            insD(lst[rr], (__float_as_uint(acc[ti][0][r]) & 0xFFFFC000u) | cv0);
            insD(lst[rr], (__float_as_uint(acc[ti][1][r]) & 0xFFFFC000u) | cv1);
        }
}

// ---------------------------------------------------------------------------
// Kernel B: bf16 MFMA scoring + med3 top-4 + FUSED finalize tail.
// R8 lesson: hipLaunchCooperativeKernel fails under the harness's graph
// capture (absmax == max|ref| -> launch never ran). Same fusion goal,
// capture-safe mechanism: split-K "last-arriver finalizes" pattern. The 8
// split-blocks of row-group bx each: candK stores -> __threadfence()
// (release: wbl2 to coherence point) -> __syncthreads -> tid0
// atomicAdd(&cnt[bx],1) (device-scope, m20). Winner (old==7) re-fences
// (acquire: L2 inv) and runs the R7-proven bitonic-merge + exact re-rank
// for its 256 rows. Atomic total order on cnt[bx] => all 8 slices visible.
// No spinning -> deadlock impossible; plain launches -> capture-safe.
// knn LEDGER (closed, do not re-attempt): R1 dbuf +8% kept; R2 ping-pong 0
// kept; R3 T19 -12% spill; R4 (256,4) = 128-TOTAL-reg budget spill 567us;
// R5 SPLITS16 occupancy unchanged (VGPR+AGPR>170); R6 body-dup spill.
// 88-95us = floor at 2 waves/SIMD.
// ---------------------------------------------------------------------------
__global__ __launch_bounds__(256, 2) void knn_tops_kernel(
    const float* __restrict__ q, const float* __restrict__ mem,
    const __hip_bfloat16* __restrict__ qb, const __hip_bfloat16* __restrict__ mb,
    const float* __restrict__ m2b, const float* __restrict__ q2,
    const float* __restrict__ m2, const float* __restrict__ scaleb,
    unsigned* __restrict__ candK, unsigned* __restrict__ cnt,
    float* __restrict__ out) {
    __shared__ __align__(16) unsigned char smem[65536];  // tiles / merge ovl
    const int tid = threadIdx.x;
    const int w = tid >> 6;
    const int lane = tid & 63;
    const int i16 = lane & 15;
    const int g = lane >> 4;
    const int row0 = blockIdx.x * BROWS;
    const int col0 = blockIdx.y * COLS_PER_SPLIT;

    // ---- A fragments: 4 row-tiles x 4 k-steps (loop-invariant) ----
    bf16x8 afrag[4][4];
#pragma unroll
    for (int ti = 0; ti < 4; ++ti) {
        const __hip_bfloat16* qrow =
            qb + (size_t)(row0 + w * 64 + ti * 16 + i16) * DIM;
#pragma unroll
        for (int ks = 0; ks < 4; ++ks)
            afrag[ti][ks] = *reinterpret_cast<const bf16x8*>(qrow + ks * 32 + g * 8);
    }

    // ---- sorted lists (packed keys), 16 rows x 4, ascending ----
    unsigned lst[16][LLIST];
#pragma unroll
    for (int rr = 0; rr < 16; ++rr)
#pragma unroll
        for (int j = 0; j < LLIST; ++j) lst[rr][j] = 0xFFFFFFFFu;

    // ---- loop-invariant addressing ----
    const int lds_base = i16 * 256 + ((g ^ (i16 & 7)) << 4);
    int soff[8];
#pragma unroll
    for (int it = 0; it < 8; ++it) {
        int fg = w * 512 + it * 64 + lane;
        int c = fg >> 4, sg = fg & 15;
        int gk = (sg & 8) | ((sg ^ c) & 7);
        soff[it] = c * DIM + gk * 8;
    }
    const __hip_bfloat16* mbt = mb + (size_t)col0 * DIM;

    // ---- ping-pong accumulators; B primed with dummy ----
    f32x4 accA[4][2], accB[4][2];
#pragma unroll
    for (int ti = 0; ti < 4; ++ti)
#pragma unroll
        for (int c2 = 0; c2 < 2; ++c2)
            accB[ti][c2] = (f32x4){BIGF, BIGF, BIGF, BIGF};
    unsigned pcv0 = 0, pcv1 = 0;

    // ---- prologue: stage tile 0 into buffer 0 ----
#pragma unroll
    for (int it = 0; it < 8; ++it)
        gl2lds16(mbt + soff[it], smem + w * 8192 + it * 1024);
    mbt += 128 * DIM;

    for (int t = 0; t < ITERS; ++t) {
        __syncthreads();  // drains tile-t staging; buffer (t+1)&1 now free
        const unsigned char* cbuf = smem + ((t & 1) << 15);
        if (t + 1 < ITERS) {
            unsigned char* nbuf = smem + (((t + 1) & 1) << 15);
#pragma unroll
            for (int it = 0; it < 8; ++it)
                gl2lds16(mbt + soff[it], nbuf + w * 8192 + it * 1024);
            mbt += 128 * DIM;
        }

        // per-tile m2b + col constants (8 column-groups of 16)
        float m2r[8];
        unsigned colv[8];
#pragma unroll
        for (int cg = 0; cg < 8; ++cg) {
            int cl = col0 + t * 128 + cg * 16 + i16;
            m2r[cg] = m2b[cl];
            colv[cg] = (unsigned)cl;
        }

        // ---- pipelined: MFMA(chunk c) issued before SELECT(chunk c-1) ----
        mfma_chunk(cbuf, lds_base, afrag, m2r, 0, accA);
        select_chunk(lst, accB, pcv0, pcv1);          // pending from prev tile
        mfma_chunk(cbuf, lds_base, afrag, m2r, 1, accB);
        select_chunk(lst, accA, colv[0], colv[1]);
        mfma_chunk(cbuf, lds_base, afrag, m2r, 2, accA);
        select_chunk(lst, accB, colv[2], colv[3]);
        mfma_chunk(cbuf, lds_base, afrag, m2r, 3, accB);
        select_chunk(lst, accA, colv[4], colv[5]);
        pcv0 = colv[6];
        pcv1 = colv[7];
    }
    // drain the last pending chunk (tile 15, chunk 3)
    select_chunk(lst, accB, pcv0, pcv1);

    __syncthreads();  // tile LDS dead; overlay merge buffer

    // ---- phase 1: SNAPSHOT partner's 4 keys, then insert ----
#pragma unroll
    for (int rr = 0; rr < 16; ++rr) {
        unsigned pv[LLIST];
#pragma unroll
        for (int j = 0; j < LLIST; ++j)
            pv[j] = (unsigned)__shfl_xor((int)lst[rr][j], 8, 64);
#pragma unroll
        for (int j = 0; j < LLIST; ++j) insD(lst[rr], pv[j]);
    }
    // ---- dump: 8 lanes x 4 keys per row, stride 33 ([256][33] = 33.8 KB) ----
    unsigned* MG = (unsigned*)smem;
    if (i16 < 8) {
#pragma unroll
        for (int rr = 0; rr < 16; ++rr) {
            int row = w * 64 + (rr >> 2) * 16 + g * 4 + (rr & 3);
#pragma unroll
            for (int j = 0; j < LLIST; ++j)
                MG[row * 33 + i16 * LLIST + j] = lst[rr][j];
        }
    }
    __syncthreads();
    // ---- phase 2: all 256 threads, one per row; med3 depth-8 over 32 keys ----
    {
        unsigned bk[TSEL];
#pragma unroll
        for (int j = 0; j < TSEL; ++j) bk[j] = 0xFFFFFFFFu;
        for (int c = 0; c < 32; ++c) {
            unsigned k = MG[tid * 33 + c];
            insD(bk, k);
        }
        size_t base = (size_t)(row0 + tid) * (SPLITS * TSEL) + blockIdx.y * TSEL;
        *reinterpret_cast<uint4*>(candK + base) =
            make_uint4(bk[0], bk[1], bk[2], bk[3]);
        *reinterpret_cast<uint4*>(candK + base + 4) =
            make_uint4(bk[4], bk[5], bk[6], bk[7]);
    }

    // ================= fused finalize: last-arriver pattern =================
    __threadfence();   // release: this thread's candK stores -> coherence pt
    __syncthreads();   // all threads' stores+fences done; MG dead
    if (tid == 0)
        *(unsigned*)smem = atomicAdd(&cnt[blockIdx.x], 1u);  // device-scope
    __syncthreads();
    if (*(unsigned*)smem != SPLITS - 1) return;  // not the last arriver
    __threadfence();   // acquire: invalidate; see all 8 splits' candK

    for (int qi = 0; qi < 64; ++qi) {
        int n = row0 + w * 64 + qi;  // wave w owns 64 consecutive rows
        // ---- in-wave merge: bitonic sort 64 keys ascending across lanes ----
        unsigned v64 = candK[(size_t)n * (SPLITS * TSEL) + lane];
#pragma unroll
        for (int k = 2; k <= 64; k <<= 1) {
#pragma unroll
            for (int j = k >> 1; j > 0; j >>= 1) {
                unsigned ov = (unsigned)__shfl_xor((int)v64, j, 64);
                unsigned mn = min(v64, ov), mx = max(v64, ov);
                bool up = ((lane & k) == 0);
                v64 = (((lane & j) == 0) == up) ? mn : mx;
            }
        }
        int cand = lane >> 2, qd = lane & 3;
        int ci = (int)((unsigned)__shfl((int)v64, cand, 64) & 0x3FFFu);

        const float4* qr =
            reinterpret_cast<const float4*>(q + (size_t)n * DIM) + qd * 8;
        const float4* mr =
            reinterpret_cast<const float4*>(mem + (size_t)ci * DIM) + qd * 8;
        float dot = 0.f;
#pragma unroll
        for (int k = 0; k < 8; ++k) {
            float4 a = qr[k], b = mr[k];
            dot = fmaf(a.x, b.x,
                       fmaf(a.y, b.y, fmaf(a.z, b.z, fmaf(a.w, b.w, dot))));
        }
        dot += __shfl_xor(dot, 1, 64);
        dot += __shfl_xor(dot, 2, 64);
        float v = (qd == 0) ? (q2[n] + m2[ci] - 2.f * dot) : BIGF;

        float dk[KNN];
        int ik[KNN];
#pragma unroll
        for (int r = 0; r < KNN; ++r) {
            float mv = v;
            int ml = lane;
#pragma unroll
            for (int off = 32; off > 0; off >>= 1) {
                float ov = __shfl_xor(mv, off, 64);
                int ol = __shfl_xor(ml, off, 64);
                if (ov < mv || (ov == mv && ol < ml)) { mv = ov; ml = ol; }
            }
            dk[r] = sqrtf(fmaxf(mv, 1e-12f));
            ik[r] = __shfl(ci, ml, 64);
            if (lane == ml) v = BIGF;
        }
        if (lane == 0) {
            float dmin = dk[0];
            float se = 0.f, wd = 0.f, sm = 0.f, ssc = 0.f;
#pragma unroll
            for (int j = 0; j < KNN; ++j) {
                float e = expf(-(dk[j] - dmin));
                se += e;
                wd = fmaf(e, dk[j], wd);
                sm += dk[j];
                ssc += scaleb[ik[j]];
            }
            wd /= se;
            float scale = ssc * 0.2f;
            float nd = wd / fmaxf(scale, 1e-6f);
            float mean = sm * 0.2f;
            float var = 0.f;
#pragma unroll
            for (int j = 0; j < KNN; ++j) {
                float dd = dk[j] - mean;
                var = fmaf(dd, dd, var);
            }
            var *= 0.2f;
            float cons = sqrtf(var) / fmaxf(mean, 1e-6f);
            out[n] = nd * (1.f + 0.5f * cons);
        }
    }
}

// ---------------------------------------------------------------------------
// ws: q2[N] | m2[M] | m2b[M] | qb bf16 | mb bf16(-2x) | candK[N*64] |
// cnt[64]  (~14 MB)
// ---------------------------------------------------------------------------
extern "C" void kernel_launch(void* const* d_in, const int* in_sizes, int n_in,
                              void* d_out, int out_size, void* d_ws,
                              size_t ws_size, hipStream_t stream) {
    const float* query  = (const float*)d_in[0];
    const float* mem    = (const float*)d_in[1];
    const float* scaleb = (const float*)d_in[2];
    float* out = (float*)d_out;

    float* q2 = (float*)d_ws;
    float* m2 = q2 + N_Q;
    float* m2b = m2 + N_M;
    __hip_bfloat16* qb = (__hip_bfloat16*)(m2b + N_M);
    __hip_bfloat16* mb = qb + (size_t)N_Q * DIM;
    unsigned* candK = (unsigned*)(mb + (size_t)N_M * DIM);
    unsigned* cnt = candK + (size_t)N_Q * SPLITS * TSEL;

    prep_kernel<<<(N_Q + N_M) / 4, 256, 0, stream>>>(query, mem, q2, m2, m2b,
                                                     qb, mb, cnt);
    dim3 gridB(N_Q / BROWS, SPLITS);
    knn_tops_kernel<<<gridB, 256, 0, stream>>>(query, mem, qb, mb, m2b, q2, m2,
                                               scaleb, candK, cnt, out);
}

// Round 10
// 193.738 us; speedup vs baseline: 3.1988x; 3.1988x over previous
//
#include <hip/hip_runtime.h>
#include <hip/hip_bf16.h>
#include <math.h>

#define N_Q 16384
#define N_M 16384
#define DIM 128
#define KNN 5
#define SPLITS 8
#define COLS_PER_SPLIT (N_M / SPLITS)   // 2048
#define ITERS (COLS_PER_SPLIT / 128)    // 16
#define BROWS 256                        // rows per block (4 waves x 64)
#define TSEL 8                           // keys kept per (row, split)
#define LLIST 4                          // per-lane sorted list depth
#define BIGF 3.0e38f

typedef __bf16 bf16x8 __attribute__((ext_vector_type(8)));
typedef float f32x4 __attribute__((ext_vector_type(4)));

__device__ __forceinline__ void gl2lds16(const void* g, void* l) {
    __builtin_amdgcn_global_load_lds(
        (const __attribute__((address_space(1))) void*)g,
        (__attribute__((address_space(3))) void*)l, 16, 0, 0);
}

// med3: with a<=b (sorted list invariant), med3(a,b,k) == max(a, min(b,k)).
__device__ __forceinline__ unsigned umed3(unsigned a, unsigned b, unsigned c) {
    unsigned d;
    asm("v_med3_u32 %0, %1, %2, %3" : "=v"(d) : "v"(a), "v"(b), "v"(c));
    return d;
}

// branchless sorted insert (ascending), depth D: (D-1) med3 + 1 min.
template <int D>
__device__ __forceinline__ void insD(unsigned (&L)[D], unsigned k) {
#pragma unroll
    for (int i = D - 1; i >= 1; --i) L[i] = umed3(L[i - 1], L[i], k);
    L[0] = min(L[0], k);
}

// ---------------------------------------------------------------------------
// Kernel A: MEM-SIDE ONLY prep (R10: query side moved into knn prologue /
// finalize inline -> prep traffic halves). Wave per memory row: sumsq +
// bf16(-2x) conversion + biased m2b.
// ---------------------------------------------------------------------------
__global__ void prep_kernel(const float* __restrict__ mem,
                            float* __restrict__ m2, float* __restrict__ m2b,
                            __hip_bfloat16* __restrict__ mb) {
    int gt = blockIdx.x * blockDim.x + threadIdx.x;
    int r = gt >> 6;
    int lane = gt & 63;
    float2 v = reinterpret_cast<const float2*>(mem + (size_t)r * DIM)[lane];
    __hip_bfloat162 bv;
    bv.x = __float2bfloat16(-2.0f * v.x);   // B operand carries the -2 factor
    bv.y = __float2bfloat16(-2.0f * v.y);
    reinterpret_cast<__hip_bfloat162*>(mb + (size_t)r * DIM)[lane] = bv;
    float s = fmaf(v.x, v.x, v.y * v.y);
#pragma unroll
    for (int off = 32; off > 0; off >>= 1) s += __shfl_down(s, off, 64);
    if (lane == 0) {
        m2[r] = s;
        m2b[r] = s + 256.0f;  // key = m2b-2dot >= ~216 > 0 always
    }
}

// ---- MFMA for one chunk (2 column-groups of 16) into the given acc set ----
__device__ __forceinline__ void mfma_chunk(const unsigned char* cbuf,
                                           int lds_base,
                                           const bf16x8 (&afrag)[4][4],
                                           const float (&m2r)[8], int c,
                                           f32x4 (&acc)[4][2]) {
#pragma unroll
    for (int ti = 0; ti < 4; ++ti)
#pragma unroll
        for (int c2 = 0; c2 < 2; ++c2) {
            float m = m2r[c * 2 + c2];
            acc[ti][c2] = (f32x4){m, m, m, m};
        }
#pragma unroll
    for (int ks = 0; ks < 4; ++ks) {
        const unsigned char* bp =
            cbuf + (lds_base ^ (ks << 6)) + (c >> 1) * 16384;
#pragma unroll
        for (int c2 = 0; c2 < 2; ++c2) {
            bf16x8 bfr = *reinterpret_cast<const bf16x8*>(
                bp + ((c & 1) * 2 + c2) * 4096);
#pragma unroll
            for (int ti = 0; ti < 4; ++ti)
                acc[ti][c2] = __builtin_amdgcn_mfma_f32_16x16x32_bf16(
                    afrag[ti][ks], bfr, acc[ti][c2], 0, 0, 0);
        }
    }
}

// ---- pack + insert the 32 keys of one finished chunk ----
__device__ __forceinline__ void select_chunk(unsigned (&lst)[16][LLIST],
                                             const f32x4 (&acc)[4][2],
                                             unsigned cv0, unsigned cv1) {
#pragma unroll
    for (int ti = 0; ti < 4; ++ti)
#pragma unroll
        for (int r = 0; r < 4; ++r) {
            const int rr = ti * 4 + r;
            insD(lst[rr], (__float_as_uint(acc[ti][0][r]) & 0xFFFFC000u) | cv0);
            insD(lst[rr], (__float_as_uint(acc[ti][1][r]) & 0xFFFFC000u) | cv1);
        }
}

// ---------------------------------------------------------------------------
// Kernel B: bf16 MFMA scoring + branchless med3 top-4 selection.
// R7-verbatim loop (benched ~95us). R10 change: afrag converted in-register
// from fp32 q (same __float2bfloat16 RNE as old prep -> bit-identical
// fragments); kills the qb workspace round-trip. Once-per-block cost.
// LEDGER (closed): R1 dbuf +8%; R2 ping-pong 0; R3 T19 -12% spill; R4
// (256,4)=128-TOTAL-reg spill; R5 SPLITS16 occupancy unchanged; R6 body-dup
// spill; R8 cooperative launch illegal under graph capture; R9 device-fence
// fusion +485us (wbl2/inv cost). 2 waves/SIMD + in-order issue = floor.
// ---------------------------------------------------------------------------
__global__ __launch_bounds__(256, 2) void knn_tops_kernel(
    const float* __restrict__ q, const __hip_bfloat16* __restrict__ mb,
    const float* __restrict__ m2b, unsigned* __restrict__ candK) {
    __shared__ __align__(16) unsigned char smem[65536];  // 2x32KB tiles; merge ovl
    const int tid = threadIdx.x;
    const int w = tid >> 6;
    const int lane = tid & 63;
    const int i16 = lane & 15;
    const int g = lane >> 4;
    const int row0 = blockIdx.x * BROWS;
    const int col0 = blockIdx.y * COLS_PER_SPLIT;

    // ---- A fragments: 4 row-tiles x 4 k-steps, cvt from fp32 q ----
    bf16x8 afrag[4][4];
#pragma unroll
    for (int ti = 0; ti < 4; ++ti) {
        const float* qrow = q + (size_t)(row0 + w * 64 + ti * 16 + i16) * DIM;
#pragma unroll
        for (int ks = 0; ks < 4; ++ks) {
            const float4* p =
                reinterpret_cast<const float4*>(qrow + ks * 32 + g * 8);
            float4 a = p[0], b = p[1];
            __align__(16) __hip_bfloat162 t[4];
            t[0].x = __float2bfloat16(a.x); t[0].y = __float2bfloat16(a.y);
            t[1].x = __float2bfloat16(a.z); t[1].y = __float2bfloat16(a.w);
            t[2].x = __float2bfloat16(b.x); t[2].y = __float2bfloat16(b.y);
            t[3].x = __float2bfloat16(b.z); t[3].y = __float2bfloat16(b.w);
            afrag[ti][ks] = *reinterpret_cast<const bf16x8*>(t);
        }
    }

    // ---- sorted lists (packed keys), 16 rows x 4, ascending ----
    unsigned lst[16][LLIST];
#pragma unroll
    for (int rr = 0; rr < 16; ++rr)
#pragma unroll
        for (int j = 0; j < LLIST; ++j) lst[rr][j] = 0xFFFFFFFFu;

    // ---- loop-invariant addressing ----
    const int lds_base = i16 * 256 + ((g ^ (i16 & 7)) << 4);
    int soff[8];
#pragma unroll
    for (int it = 0; it < 8; ++it) {
        int fg = w * 512 + it * 64 + lane;
        int c = fg >> 4, sg = fg & 15;
        int gk = (sg & 8) | ((sg ^ c) & 7);
        soff[it] = c * DIM + gk * 8;
    }
    const __hip_bfloat16* mbt = mb + (size_t)col0 * DIM;

    // ---- ping-pong accumulators; B primed with dummy ----
    f32x4 accA[4][2], accB[4][2];
#pragma unroll
    for (int ti = 0; ti < 4; ++ti)
#pragma unroll
        for (int c2 = 0; c2 < 2; ++c2)
            accB[ti][c2] = (f32x4){BIGF, BIGF, BIGF, BIGF};
    unsigned pcv0 = 0, pcv1 = 0;

    // ---- prologue: stage tile 0 into buffer 0 ----
#pragma unroll
    for (int it = 0; it < 8; ++it)
        gl2lds16(mbt + soff[it], smem + w * 8192 + it * 1024);
    mbt += 128 * DIM;

    for (int t = 0; t < ITERS; ++t) {
        __syncthreads();  // drains tile-t staging; buffer (t+1)&1 now free
        const unsigned char* cbuf = smem + ((t & 1) << 15);
        if (t + 1 < ITERS) {
            unsigned char* nbuf = smem + (((t + 1) & 1) << 15);
#pragma unroll
            for (int it = 0; it < 8; ++it)
                gl2lds16(mbt + soff[it], nbuf + w * 8192 + it * 1024);
            mbt += 128 * DIM;
        }

        // per-tile m2b + col constants (8 column-groups of 16)
        float m2r[8];
        unsigned colv[8];
#pragma unroll
        for (int cg = 0; cg < 8; ++cg) {
            int cl = col0 + t * 128 + cg * 16 + i16;
            m2r[cg] = m2b[cl];
            colv[cg] = (unsigned)cl;
        }

        // ---- pipelined: MFMA(chunk c) issued before SELECT(chunk c-1) ----
        mfma_chunk(cbuf, lds_base, afrag, m2r, 0, accA);
        select_chunk(lst, accB, pcv0, pcv1);          // pending from prev tile
        mfma_chunk(cbuf, lds_base, afrag, m2r, 1, accB);
        select_chunk(lst, accA, colv[0], colv[1]);
        mfma_chunk(cbuf, lds_base, afrag, m2r, 2, accA);
        select_chunk(lst, accB, colv[2], colv[3]);
        mfma_chunk(cbuf, lds_base, afrag, m2r, 3, accB);
        select_chunk(lst, accA, colv[4], colv[5]);
        pcv0 = colv[6];
        pcv1 = colv[7];
    }
    // drain the last pending chunk (tile 15, chunk 3)
    select_chunk(lst, accB, pcv0, pcv1);

    __syncthreads();  // tile LDS dead; overlay merge buffer

    // ---- phase 1: SNAPSHOT partner's 4 keys, then insert ----
#pragma unroll
    for (int rr = 0; rr < 16; ++rr) {
        unsigned pv[LLIST];
#pragma unroll
        for (int j = 0; j < LLIST; ++j)
            pv[j] = (unsigned)__shfl_xor((int)lst[rr][j], 8, 64);
#pragma unroll
        for (int j = 0; j < LLIST; ++j) insD(lst[rr], pv[j]);
    }
    // ---- dump: 8 lanes x 4 keys per row, stride 33 ([256][33] = 33.8 KB) ----
    unsigned* MG = (unsigned*)smem;
    if (i16 < 8) {
#pragma unroll
        for (int rr = 0; rr < 16; ++rr) {
            int row = w * 64 + (rr >> 2) * 16 + g * 4 + (rr & 3);
#pragma unroll
            for (int j = 0; j < LLIST; ++j)
                MG[row * 33 + i16 * LLIST + j] = lst[rr][j];
        }
    }
    __syncthreads();
    // ---- phase 2: all 256 threads, one per row; med3 depth-8 over 32 keys ----
    {
        unsigned bk[TSEL];
#pragma unroll
        for (int j = 0; j < TSEL; ++j) bk[j] = 0xFFFFFFFFu;
        for (int c = 0; c < 32; ++c) {
            unsigned k = MG[tid * 33 + c];
            insD(bk, k);
        }
        size_t base = (size_t)(row0 + tid) * (SPLITS * TSEL) + blockIdx.y * TSEL;
        *reinterpret_cast<uint4*>(candK + base) =
            make_uint4(bk[0], bk[1], bk[2], bk[3]);
        *reinterpret_cast<uint4*>(candK + base + 4) =
            make_uint4(bk[4], bk[5], bk[6], bk[7]);
    }
}

// ---------------------------------------------------------------------------
// Kernel D: fused merge (in-wave bitonic over 64 keys) + exact fp32 re-rank
// + adaptive-KNN output. R10: q2 computed INLINE from the q-row loads the
// dot product already does (one extra fma chain + the same 2 shuffles) ->
// prep's query pass deleted.
// ---------------------------------------------------------------------------
__global__ __launch_bounds__(256) void finalize_kernel(
    const float* __restrict__ q, const float* __restrict__ mem,
    const float* __restrict__ m2, const unsigned* __restrict__ candK,
    const float* __restrict__ scaleb, float* __restrict__ out) {
    int wv = threadIdx.x >> 6, lane = threadIdx.x & 63;
    int n = blockIdx.x * 4 + wv;

    // ---- in-wave merge: bitonic sort 64 keys ascending across lanes ----
    unsigned v64 = candK[(size_t)n * (SPLITS * TSEL) + lane];
#pragma unroll
    for (int k = 2; k <= 64; k <<= 1) {
#pragma unroll
        for (int j = k >> 1; j > 0; j >>= 1) {
            unsigned ov = (unsigned)__shfl_xor((int)v64, j, 64);
            unsigned mn = min(v64, ov), mx = max(v64, ov);
            bool up = ((lane & k) == 0);
            v64 = (((lane & j) == 0) == up) ? mn : mx;
        }
    }
    int cand = lane >> 2, qd = lane & 3;
    int ci = (int)((unsigned)__shfl((int)v64, cand, 64) & 0x3FFFu);

    const float4* qr = reinterpret_cast<const float4*>(q + (size_t)n * DIM) + qd * 8;
    const float4* mr = reinterpret_cast<const float4*>(mem + (size_t)ci * DIM) + qd * 8;
    float dot = 0.f, s2 = 0.f;
#pragma unroll
    for (int k = 0; k < 8; ++k) {
        float4 a = qr[k], b = mr[k];
        dot = fmaf(a.x, b.x, fmaf(a.y, b.y, fmaf(a.z, b.z, fmaf(a.w, b.w, dot))));
        s2  = fmaf(a.x, a.x, fmaf(a.y, a.y, fmaf(a.z, a.z, fmaf(a.w, a.w, s2))));
    }
    dot += __shfl_xor(dot, 1, 64);
    dot += __shfl_xor(dot, 2, 64);
    s2  += __shfl_xor(s2, 1, 64);
    s2  += __shfl_xor(s2, 2, 64);
    float v = (qd == 0) ? (s2 + m2[ci] - 2.f * dot) : BIGF;

    float dk[KNN]; int ik[KNN];
#pragma unroll
    for (int r = 0; r < KNN; ++r) {
        float mv = v; int ml = lane;
#pragma unroll
        for (int off = 32; off > 0; off >>= 1) {
            float ov = __shfl_xor(mv, off, 64);
            int   ol = __shfl_xor(ml, off, 64);
            if (ov < mv || (ov == mv && ol < ml)) { mv = ov; ml = ol; }
        }
        dk[r] = sqrtf(fmaxf(mv, 1e-12f));
        ik[r] = __shfl(ci, ml, 64);
        if (lane == ml) v = BIGF;
    }
    if (lane == 0) {
        float dmin = dk[0];
        float se = 0.f, wd = 0.f, sm = 0.f, ssc = 0.f;
#pragma unroll
        for (int j = 0; j < KNN; ++j) {
            float e = expf(-(dk[j] - dmin));
            se += e;
            wd = fmaf(e, dk[j], wd);
            sm += dk[j];
            ssc += scaleb[ik[j]];
        }
        wd /= se;
        float scale = ssc * 0.2f;
        float nd = wd / fmaxf(scale, 1e-6f);
        float mean = sm * 0.2f;
        float var = 0.f;
#pragma unroll
        for (int j = 0; j < KNN; ++j) {
            float dd = dk[j] - mean;
            var = fmaf(dd, dd, var);
        }
        var *= 0.2f;
        float cons = sqrtf(var) / fmaxf(mean, 1e-6f);
        out[n] = nd * (1.f + 0.5f * cons);
    }
}

// ---------------------------------------------------------------------------
// ws: m2[M] | m2b[M] | mb bf16(-2x) | candK[N*64]  (~8.4 MB)
// ---------------------------------------------------------------------------
extern "C" void kernel_launch(void* const* d_in, const int* in_sizes, int n_in,
                              void* d_out, int out_size, void* d_ws,
                              size_t ws_size, hipStream_t stream) {
    const float* query  = (const float*)d_in[0];
    const float* mem    = (const float*)d_in[1];
    const float* scaleb = (const float*)d_in[2];
    float* out = (float*)d_out;

    float* m2 = (float*)d_ws;
    float* m2b = m2 + N_M;
    __hip_bfloat16* mb = (__hip_bfloat16*)(m2b + N_M);
    unsigned* candK = (unsigned*)(mb + (size_t)N_M * DIM);

    prep_kernel<<<N_M / 4, 256, 0, stream>>>(mem, m2, m2b, mb);
    dim3 gridB(N_Q / BROWS, SPLITS);
    knn_tops_kernel<<<gridB, 256, 0, stream>>>(query, mb, m2b, candK);
    finalize_kernel<<<N_Q / 4, 256, 0, stream>>>(query, mem, m2, candK,
                                                 scaleb, out);
}

// Round 11
// 188.431 us; speedup vs baseline: 3.2889x; 1.0282x over previous
//
#include <hip/hip_runtime.h>
#include <hip/hip_bf16.h>
#include <math.h>

#define N_Q 16384
#define N_M 16384
#define DIM 128
#define KNN 5
#define SPLITS 8
#define COLS_PER_SPLIT (N_M / SPLITS)   // 2048
#define ITERS (COLS_PER_SPLIT / 128)    // 16
#define BROWS 256                        // rows per block (4 waves x 64)
#define TSEL 8                           // keys kept per (row, split)
#define LLIST 4                          // per-lane sorted list depth
#define BIGF 3.0e38f

typedef __bf16 bf16x8 __attribute__((ext_vector_type(8)));
typedef float f32x4 __attribute__((ext_vector_type(4)));

__device__ __forceinline__ void gl2lds16(const void* g, void* l) {
    __builtin_amdgcn_global_load_lds(
        (const __attribute__((address_space(1))) void*)g,
        (__attribute__((address_space(3))) void*)l, 16, 0, 0);
}

// med3: with a<=b (sorted list invariant), med3(a,b,k) == max(a, min(b,k)).
__device__ __forceinline__ unsigned umed3(unsigned a, unsigned b, unsigned c) {
    unsigned d;
    asm("v_med3_u32 %0, %1, %2, %3" : "=v"(d) : "v"(a), "v"(b), "v"(c));
    return d;
}

// branchless sorted insert (ascending), depth D: (D-1) med3 + 1 min.
template <int D>
__device__ __forceinline__ void insD(unsigned (&L)[D], unsigned k) {
#pragma unroll
    for (int i = D - 1; i >= 1; --i) L[i] = umed3(L[i - 1], L[i], k);
    L[0] = min(L[0], k);
}

// ---------------------------------------------------------------------------
// Kernel A: per-row sumsq + bf16 conversion + biased m2.
// mb is stored PRE-SCALED by -2 (exact in bf16): MFMA with C=m2b directly
// produces key score s = m2+256-2dot > 0 (uint order == score order).
// (R10 tried mem-side-only prep + in-knn q conversion: the conversion is
// 8x-redundant across split-blocks -> net -4us. Full prep restored.)
// ---------------------------------------------------------------------------
__global__ void prep_kernel(const float* __restrict__ q,
                            const float* __restrict__ mem,
                            float* __restrict__ q2, float* __restrict__ m2,
                            float* __restrict__ m2b,
                            __hip_bfloat16* __restrict__ qb,
                            __hip_bfloat16* __restrict__ mb) {
    int gt = blockIdx.x * blockDim.x + threadIdx.x;
    int wid = gt >> 6;
    int lane = gt & 63;
    bool isq = wid < N_Q;
    int r = isq ? wid : wid - N_Q;
    const float* src = (isq ? q : mem) + (size_t)r * DIM;
    __hip_bfloat16* bdst = (isq ? qb : mb) + (size_t)r * DIM;
    float2 v = reinterpret_cast<const float2*>(src)[lane];
    float sc = isq ? 1.0f : -2.0f;   // B operand carries the -2 factor
    __hip_bfloat162 bv;
    bv.x = __float2bfloat16(sc * v.x);
    bv.y = __float2bfloat16(sc * v.y);
    reinterpret_cast<__hip_bfloat162*>(bdst)[lane] = bv;
    float s = fmaf(v.x, v.x, v.y * v.y);
#pragma unroll
    for (int off = 32; off > 0; off >>= 1) s += __shfl_down(s, off, 64);
    if (lane == 0) {
        if (isq) {
            q2[r] = s;
        } else {
            m2[r] = s;
            m2b[r] = s + 256.0f;  // key = m2b-2dot >= ~216 > 0 always
        }
    }
}

// ---- MFMA for one chunk (2 column-groups of 16) into the given acc set ----
__device__ __forceinline__ void mfma_chunk(const unsigned char* cbuf,
                                           int lds_base,
                                           const bf16x8 (&afrag)[4][4],
                                           const float (&m2r)[8], int c,
                                           f32x4 (&acc)[4][2]) {
#pragma unroll
    for (int ti = 0; ti < 4; ++ti)
#pragma unroll
        for (int c2 = 0; c2 < 2; ++c2) {
            float m = m2r[c * 2 + c2];
            acc[ti][c2] = (f32x4){m, m, m, m};
        }
#pragma unroll
    for (int ks = 0; ks < 4; ++ks) {
        const unsigned char* bp =
            cbuf + (lds_base ^ (ks << 6)) + (c >> 1) * 16384;
#pragma unroll
        for (int c2 = 0; c2 < 2; ++c2) {
            bf16x8 bfr = *reinterpret_cast<const bf16x8*>(
                bp + ((c & 1) * 2 + c2) * 4096);
#pragma unroll
            for (int ti = 0; ti < 4; ++ti)
                acc[ti][c2] = __builtin_amdgcn_mfma_f32_16x16x32_bf16(
                    afrag[ti][ks], bfr, acc[ti][c2], 0, 0, 0);
        }
    }
}

// ---- pack + insert the 32 keys of one finished chunk ----
__device__ __forceinline__ void select_chunk(unsigned (&lst)[16][LLIST],
                                             const f32x4 (&acc)[4][2],
                                             unsigned cv0, unsigned cv1) {
#pragma unroll
    for (int ti = 0; ti < 4; ++ti)
#pragma unroll
        for (int r = 0; r < 4; ++r) {
            const int rr = ti * 4 + r;
            insD(lst[rr], (__float_as_uint(acc[ti][0][r]) & 0xFFFFC000u) | cv0);
            insD(lst[rr], (__float_as_uint(acc[ti][1][r]) & 0xFFFFC000u) | cv1);
        }
}

// ---------------------------------------------------------------------------
// Kernel B: bf16 MFMA scoring + branchless med3 top-4 selection.
// R7-VERBATIM (best measured: knn ~95us, total 189.9). LEDGER (closed):
// R1 dbuf 97->90 kept; R2 ping-pong 0 kept; R3 T19 sched pin -12% spill;
// R4 (256,4) = 128-TOTAL-reg (VGPR+AGPR unified file!) budget -> full
// spill 567us; R5 SPLITS16: occupancy stayed 2 blk/CU (working set ~190
// total regs > 512/3 -> 2 waves/SIMD hard cap); R6 flip-branch body-dup
// blew combined 256 budget -> spill; R8 hipLaunchCooperativeKernel fails
// under graph capture (silent no-launch); R9 device-scope threadfence =
// wbl2/inv per use -> +485us; R10 q-cvt into knn = 8x redundant -> -4us.
// Structural floor: 2 waves/SIMD, in-order issue, matrix 33 + VALU ~23 +
// LDS ~27 us pipes serialize -> ~88-95us. Do not re-attempt.
// ---------------------------------------------------------------------------
__global__ __launch_bounds__(256, 2) void knn_tops_kernel(
    const __hip_bfloat16* __restrict__ qb, const __hip_bfloat16* __restrict__ mb,
    const float* __restrict__ m2b, unsigned* __restrict__ candK) {
    __shared__ __align__(16) unsigned char smem[65536];  // 2x32KB tiles; merge ovl
    const int tid = threadIdx.x;
    const int w = tid >> 6;
    const int lane = tid & 63;
    const int i16 = lane & 15;
    const int g = lane >> 4;
    const int row0 = blockIdx.x * BROWS;
    const int col0 = blockIdx.y * COLS_PER_SPLIT;

    // ---- A fragments: 4 row-tiles x 4 k-steps (loop-invariant) ----
    bf16x8 afrag[4][4];
#pragma unroll
    for (int ti = 0; ti < 4; ++ti) {
        const __hip_bfloat16* qrow =
            qb + (size_t)(row0 + w * 64 + ti * 16 + i16) * DIM;
#pragma unroll
        for (int ks = 0; ks < 4; ++ks)
            afrag[ti][ks] = *reinterpret_cast<const bf16x8*>(qrow + ks * 32 + g * 8);
    }

    // ---- sorted lists (packed keys), 16 rows x 4, ascending ----
    unsigned lst[16][LLIST];
#pragma unroll
    for (int rr = 0; rr < 16; ++rr)
#pragma unroll
        for (int j = 0; j < LLIST; ++j) lst[rr][j] = 0xFFFFFFFFu;

    // ---- loop-invariant addressing ----
    const int lds_base = i16 * 256 + ((g ^ (i16 & 7)) << 4);
    int soff[8];
#pragma unroll
    for (int it = 0; it < 8; ++it) {
        int fg = w * 512 + it * 64 + lane;
        int c = fg >> 4, sg = fg & 15;
        int gk = (sg & 8) | ((sg ^ c) & 7);
        soff[it] = c * DIM + gk * 8;
    }
    const __hip_bfloat16* mbt = mb + (size_t)col0 * DIM;

    // ---- ping-pong accumulators; B primed with dummy (evicted by any real) ----
    f32x4 accA[4][2], accB[4][2];
#pragma unroll
    for (int ti = 0; ti < 4; ++ti)
#pragma unroll
        for (int c2 = 0; c2 < 2; ++c2)
            accB[ti][c2] = (f32x4){BIGF, BIGF, BIGF, BIGF};
    unsigned pcv0 = 0, pcv1 = 0;

    // ---- prologue: stage tile 0 into buffer 0 ----
#pragma unroll
    for (int it = 0; it < 8; ++it)
        gl2lds16(mbt + soff[it], smem + w * 8192 + it * 1024);
    mbt += 128 * DIM;

    for (int t = 0; t < ITERS; ++t) {
        __syncthreads();  // drains tile-t staging; buffer (t+1)&1 now free
        const unsigned char* cbuf = smem + ((t & 1) << 15);
        if (t + 1 < ITERS) {
            unsigned char* nbuf = smem + (((t + 1) & 1) << 15);
#pragma unroll
            for (int it = 0; it < 8; ++it)
                gl2lds16(mbt + soff[it], nbuf + w * 8192 + it * 1024);
            mbt += 128 * DIM;
        }

        // per-tile m2b + col constants (8 column-groups of 16)
        float m2r[8];
        unsigned colv[8];
#pragma unroll
        for (int cg = 0; cg < 8; ++cg) {
            int cl = col0 + t * 128 + cg * 16 + i16;
            m2r[cg] = m2b[cl];
            colv[cg] = (unsigned)cl;
        }

        // ---- pipelined: MFMA(chunk c) issued before SELECT(chunk c-1) ----
        mfma_chunk(cbuf, lds_base, afrag, m2r, 0, accA);
        select_chunk(lst, accB, pcv0, pcv1);          // pending from prev tile
        mfma_chunk(cbuf, lds_base, afrag, m2r, 1, accB);
        select_chunk(lst, accA, colv[0], colv[1]);
        mfma_chunk(cbuf, lds_base, afrag, m2r, 2, accA);
        select_chunk(lst, accB, colv[2], colv[3]);
        mfma_chunk(cbuf, lds_base, afrag, m2r, 3, accB);
        select_chunk(lst, accA, colv[4], colv[5]);
        pcv0 = colv[6];
        pcv1 = colv[7];
    }
    // drain the last pending chunk (tile 15, chunk 3)
    select_chunk(lst, accB, pcv0, pcv1);

    __syncthreads();  // tile LDS dead; overlay merge buffer

    // ---- phase 1: SNAPSHOT partner's 4 keys, then insert ----
#pragma unroll
    for (int rr = 0; rr < 16; ++rr) {
        unsigned pv[LLIST];
#pragma unroll
        for (int j = 0; j < LLIST; ++j)
            pv[j] = (unsigned)__shfl_xor((int)lst[rr][j], 8, 64);
#pragma unroll
        for (int j = 0; j < LLIST; ++j) insD(lst[rr], pv[j]);
    }
    // ---- dump: 8 lanes x 4 keys per row, stride 33 ([256][33] = 33.8 KB) ----
    unsigned* MG = (unsigned*)smem;
    if (i16 < 8) {
#pragma unroll
        for (int rr = 0; rr < 16; ++rr) {
            int row = w * 64 + (rr >> 2) * 16 + g * 4 + (rr & 3);
#pragma unroll
            for (int j = 0; j < LLIST; ++j)
                MG[row * 33 + i16 * LLIST + j] = lst[rr][j];
        }
    }
    __syncthreads();
    // ---- phase 2: all 256 threads, one per row; med3 depth-8 over 32 keys ----
    {
        unsigned bk[TSEL];
#pragma unroll
        for (int j = 0; j < TSEL; ++j) bk[j] = 0xFFFFFFFFu;
        for (int c = 0; c < 32; ++c) {
            unsigned k = MG[tid * 33 + c];
            insD(bk, k);
        }
        size_t base = (size_t)(row0 + tid) * (SPLITS * TSEL) + blockIdx.y * TSEL;
        *reinterpret_cast<uint4*>(candK + base) =
            make_uint4(bk[0], bk[1], bk[2], bk[3]);
        *reinterpret_cast<uint4*>(candK + base + 4) =
            make_uint4(bk[4], bk[5], bk[6], bk[7]);
    }
}

// ---------------------------------------------------------------------------
// Kernel D: fused merge (in-wave bitonic over 64 keys) + exact fp32 re-rank
// + adaptive-KNN output. Keys are globally unique (disjoint col ranges per
// split) -> exact total order -> bit-identical candidate set.
// ---------------------------------------------------------------------------
__global__ __launch_bounds__(256) void finalize_kernel(
    const float* __restrict__ q, const float* __restrict__ mem,
    const float* __restrict__ q2, const float* __restrict__ m2,
    const unsigned* __restrict__ candK, const float* __restrict__ scaleb,
    float* __restrict__ out) {
    int wv = threadIdx.x >> 6, lane = threadIdx.x & 63;
    int n = blockIdx.x * 4 + wv;

    // ---- in-wave merge: bitonic sort 64 keys ascending across lanes ----
    unsigned v64 = candK[(size_t)n * (SPLITS * TSEL) + lane];
#pragma unroll
    for (int k = 2; k <= 64; k <<= 1) {
#pragma unroll
        for (int j = k >> 1; j > 0; j >>= 1) {
            unsigned ov = (unsigned)__shfl_xor((int)v64, j, 64);
            unsigned mn = min(v64, ov), mx = max(v64, ov);
            bool up = ((lane & k) == 0);
            v64 = (((lane & j) == 0) == up) ? mn : mx;
        }
    }
    int cand = lane >> 2, qd = lane & 3;
    int ci = (int)((unsigned)__shfl((int)v64, cand, 64) & 0x3FFFu);

    const float4* qr = reinterpret_cast<const float4*>(q + (size_t)n * DIM) + qd * 8;
    const float4* mr = reinterpret_cast<const float4*>(mem + (size_t)ci * DIM) + qd * 8;
    float dot = 0.f;
#pragma unroll
    for (int k = 0; k < 8; ++k) {
        float4 a = qr[k], b = mr[k];
        dot = fmaf(a.x, b.x, fmaf(a.y, b.y, fmaf(a.z, b.z, fmaf(a.w, b.w, dot))));
    }
    dot += __shfl_xor(dot, 1, 64);
    dot += __shfl_xor(dot, 2, 64);
    float v = (qd == 0) ? (q2[n] + m2[ci] - 2.f * dot) : BIGF;

    float dk[KNN]; int ik[KNN];
#pragma unroll
    for (int r = 0; r < KNN; ++r) {
        float mv = v; int ml = lane;
#pragma unroll
        for (int off = 32; off > 0; off >>= 1) {
            float ov = __shfl_xor(mv, off, 64);
            int   ol = __shfl_xor(ml, off, 64);
            if (ov < mv || (ov == mv && ol < ml)) { mv = ov; ml = ol; }
        }
        dk[r] = sqrtf(fmaxf(mv, 1e-12f));
        ik[r] = __shfl(ci, ml, 64);
        if (lane == ml) v = BIGF;
    }
    if (lane == 0) {
        float dmin = dk[0];
        float se = 0.f, wd = 0.f, sm = 0.f, ssc = 0.f;
#pragma unroll
        for (int j = 0; j < KNN; ++j) {
            float e = expf(-(dk[j] - dmin));
            se += e;
            wd = fmaf(e, dk[j], wd);
            sm += dk[j];
            ssc += scaleb[ik[j]];
        }
        wd /= se;
        float scale = ssc * 0.2f;
        float nd = wd / fmaxf(scale, 1e-6f);
        float mean = sm * 0.2f;
        float var = 0.f;
#pragma unroll
        for (int j = 0; j < KNN; ++j) {
            float dd = dk[j] - mean;
            var = fmaf(dd, dd, var);
        }
        var *= 0.2f;
        float cons = sqrtf(var) / fmaxf(mean, 1e-6f);
        out[n] = nd * (1.f + 0.5f * cons);
    }
}

// ---------------------------------------------------------------------------
// ws: q2[N] | m2[M] | m2b[M] | qb bf16 | mb bf16(-2x) | candK[N*64] (~14 MB)
// ---------------------------------------------------------------------------
extern "C" void kernel_launch(void* const* d_in, const int* in_sizes, int n_in,
                              void* d_out, int out_size, void* d_ws,
                              size_t ws_size, hipStream_t stream) {
    const float* query  = (const float*)d_in[0];
    const float* mem    = (const float*)d_in[1];
    const float* scaleb = (const float*)d_in[2];
    float* out = (float*)d_out;

    float* q2 = (float*)d_ws;
    float* m2 = q2 + N_Q;
    float* m2b = m2 + N_M;
    __hip_bfloat16* qb = (__hip_bfloat16*)(m2b + N_M);
    __hip_bfloat16* mb = qb + (size_t)N_Q * DIM;
    unsigned* candK = (unsigned*)(mb + (size_t)N_M * DIM);

    prep_kernel<<<(N_Q + N_M) / 4, 256, 0, stream>>>(query, mem, q2, m2, m2b,
                                                     qb, mb);
    dim3 gridB(N_Q / BROWS, SPLITS);
    knn_tops_kernel<<<gridB, 256, 0, stream>>>(qb, mb, m2b, candK);
    finalize_kernel<<<N_Q / 4, 256, 0, stream>>>(query, mem, q2, m2, candK,
                                                 scaleb, out);
}